// Round 7
// baseline (475.817 us; speedup 1.0000x reference)
//
#include <hip/hip_runtime.h>

#define T_TOK   8192
#define M_MORPH 12
#define NMORPH  (T_TOK * M_MORPH)   // 98304

typedef float f32x4 __attribute__((ext_vector_type(4)));
typedef float f32x2 __attribute__((ext_vector_type(2)));
typedef short s16x8 __attribute__((ext_vector_type(8)));

__device__ __forceinline__ float sigmoidf_(float x) {
    return __fdividef(1.f, 1.f + __expf(-x));
}

__device__ __forceinline__ int rowof(int s, int mode, int N) {
    if (mode == 0) return s;
    if (mode == 1) { int m = s % M_MORPH; return s + (M_MORPH - 1) - 2 * m; }
    return N - 1 - s;
}

// packed fp32 FMA: acc = w*h + acc (exact IEEE fma per lane-half, full rate)
#define PKFMA(acc, w, h) \
    asm("v_pk_fma_f32 %0, %1, %2, %0" : "+v"(acc) : "v"(w), "v"(h))

// lane-half swap broadcast: given v, produce
//   lo_b = v's lanes 0..31 broadcast to both halves
//   hi_b = v's lanes 32..63 broadcast to both halves
// Bit-exact replacement for shfl_xor+cndmask; 1 VALU op, no LDS.
__device__ __forceinline__ void half_swap(float v, float& lo_b, float& hi_b) {
#if __has_builtin(__builtin_amdgcn_permlane32_swap)
    auto r = __builtin_amdgcn_permlane32_swap(__float_as_uint(v), __float_as_uint(v),
                                              false, false);
    lo_b = __uint_as_float((unsigned)r[0]);
    hi_b = __uint_as_float((unsigned)r[1]);
#else
    const float e = __shfl_xor(v, 32);
    const bool lo = ((threadIdx.x & 63) < 32);
    lo_b = lo ? v : e;
    hi_b = lo ? e : v;
#endif
}

// ---------------------------------------------------------------------------
// Pre-split LSTM input weights into frag-ready bf16 hi/lo tables.
// ---------------------------------------------------------------------------
__global__ void prep_B(const float* __restrict__ W, const float* __restrict__ b,
                       unsigned short* __restrict__ Bh, unsigned short* __restrict__ Bl,
                       float* __restrict__ bcat, int WK, int KPAD) {
    const int n = blockIdx.x;        // 0..255
    const int k = threadIdx.x;       // 0..KPAD-1
    const int dir = n >> 7, r = n & 127;
    float v = (k < WK) ? W[(size_t)(dir * 128 + r) * WK + k] : 0.f;
    unsigned int u = __float_as_uint(v);
    unsigned short hb = (unsigned short)(u >> 16);
    float fh = __uint_as_float(u & 0xFFFF0000u);
    float lo = v - fh;
    unsigned short lb = (unsigned short)(__float_as_uint(lo) >> 16);
    Bh[(size_t)n * KPAD + k] = hb;
    Bl[(size_t)n * KPAD + k] = lb;
    if (k == 0) bcat[n] = b[dir * 128 + r];
}

// ---------------------------------------------------------------------------
// X[r][256] = A[r][AS](first KACT) @ Wcat[256][K]^T + bcat via split-bf16
// MFMA (hi*hi + hi*lo + lo*hi).
//
// PAIRED OUTPUT LAYOUT (round-5): column c is stored at
//   d*128 + (c%64)*2 + ((c%128)/64),  d = c/128
// so the chain's lane l reads its two gate pre-activations {col d*128+l,
// col d*128+64+l} as ONE dwordx2. Pure index permutation (same values).
// ---------------------------------------------------------------------------
template <int KACT, int KPAD, int AS>
__global__ __launch_bounds__(256, 2) void gemm_mfma(const float* __restrict__ A,
                                                    const unsigned short* __restrict__ Bh,
                                                    const unsigned short* __restrict__ Bl,
                                                    const float* __restrict__ bc,
                                                    float* __restrict__ X) {
    const int lane = threadIdx.x & 63;
    const int wave = threadIdx.x >> 6;
    const int col = lane & 15;
    const int kc  = (lane >> 4) * 8;
    const int row0 = blockIdx.x * 128 + wave * 32;

    f32x4 acc[2][16];
#pragma unroll
    for (int ct = 0; ct < 16; ++ct) {
        const float bv = bc[ct * 16 + col];
        f32x4 v; v[0] = bv; v[1] = bv; v[2] = bv; v[3] = bv;
        acc[0][ct] = v; acc[1][ct] = v;
    }

    const float* a0 = A + (size_t)(row0 + col) * AS;
    const float* a1 = A + (size_t)(row0 + 16 + col) * AS;

#pragma unroll
    for (int ks = 0; ks < KPAD / 32; ++ks) {
        const int kb = ks * 32 + kc;
        s16x8 ah[2], al[2];
#pragma unroll
        for (int rt = 0; rt < 2; ++rt) {
            const float* ap = (rt ? a1 : a0) + kb;
            float av[8];
#pragma unroll
            for (int h = 0; h < 2; ++h) {
                float4 t; t.x = t.y = t.z = t.w = 0.f;
                if ((ks + 1) * 32 <= KACT || kb + h * 4 < KACT)
                    t = *(const float4*)(ap + h * 4);
                av[h * 4 + 0] = t.x; av[h * 4 + 1] = t.y;
                av[h * 4 + 2] = t.z; av[h * 4 + 3] = t.w;
            }
#pragma unroll
            for (int j = 0; j < 8; ++j) {
                const unsigned int u = __float_as_uint(av[j]);
                const unsigned short hb = (unsigned short)(u >> 16);
                const float fh = __uint_as_float(u & 0xFFFF0000u);
                const float lov = av[j] - fh;
                const unsigned short lb = (unsigned short)(__float_as_uint(lov) >> 16);
                ah[rt][j] = (short)hb;
                al[rt][j] = (short)lb;
            }
        }

        const unsigned short* bhp = Bh + (size_t)col * KPAD + kb;
        const unsigned short* blp = Bl + (size_t)col * KPAD + kb;
#pragma unroll
        for (int ct = 0; ct < 16; ++ct) {
            const s16x8 bh8 = *(const s16x8*)(bhp + (size_t)ct * 16 * KPAD);
            const s16x8 bl8 = *(const s16x8*)(blp + (size_t)ct * 16 * KPAD);
#pragma unroll
            for (int rt = 0; rt < 2; ++rt) {
                acc[rt][ct] = __builtin_amdgcn_mfma_f32_16x16x32_bf16(ah[rt], bh8, acc[rt][ct], 0, 0, 0);
                acc[rt][ct] = __builtin_amdgcn_mfma_f32_16x16x32_bf16(ah[rt], bl8, acc[rt][ct], 0, 0, 0);
                acc[rt][ct] = __builtin_amdgcn_mfma_f32_16x16x32_bf16(al[rt], bh8, acc[rt][ct], 0, 0, 0);
            }
        }
    }

    const int r_in = (lane >> 4) * 4;
#pragma unroll
    for (int rt = 0; rt < 2; ++rt)
#pragma unroll
        for (int ct = 0; ct < 16; ++ct) {
            const int c = ct * 16 + col;           // original column
            const int d = c >> 7;
            const int cm = c & 127;
            const int nc = d * 128 + (cm & 63) * 2 + (cm >> 6);  // paired
#pragma unroll
            for (int i = 0; i < 4; ++i)
                X[(size_t)(row0 + rt * 16 + r_in + i) * 256 + nc] = acc[rt][ct][i];
        }
}

// ---------------------------------------------------------------------------
// Single-chunk LSTM recurrence (r6 proven version) — used for the TOKEN
// level (0.5 waves/SIMD: no intra-SIMD contention, merging would not help).
// ---------------------------------------------------------------------------
__global__ __launch_bounds__(64)
__attribute__((amdgpu_waves_per_eu(2, 2)))
void lstm_chain(const float* __restrict__ Xall,
                const float* __restrict__ Whhall,
                float* __restrict__ Hout,
                int N, int Lc, int Wu,
                int bwd_mode, int store_last) {
    __shared__ __align__(16) float sh[64];
    const int lane = threadIdx.x;
    const int dir = blockIdx.y;
    const int dm = dir ? bwd_mode : 0;
    const float* Whh = Whhall + dir * 128 * 32;

    const int cs = blockIdx.x * Lc;
    if (cs >= N) return;
    int ce = cs + Lc; if (ce > N) ce = N;
    int ws = cs - Wu; if (ws < 0) ws = 0;

    f32x2 wa[16], wb[16];
    {
        const f32x2* w1 = (const f32x2*)(Whh + lane * 32);
        const f32x2* w2 = (const f32x2*)(Whh + (lane + 64) * 32);
#pragma unroll
        for (int i = 0; i < 16; ++i) { wa[i] = w1[i]; wb[i] = w2[i]; }
    }
#pragma unroll
    for (int i = 0; i < 16; ++i) {
        asm volatile("" : "+v"(wa[i]));
        asm volatile("" : "+v"(wb[i]));
    }

    const float* Xc = Xall + dir * 128 + lane * 2;

    f32x2 q[8];
#pragma unroll
    for (int p = 0; p < 8; ++p) {
        int sp = ws + p; if (sp > ce - 1) sp = ce - 1;
        const int rp = rowof(sp, dm, N);
        q[p] = *(const f32x2*)(Xc + (size_t)rp * 256);
    }

    int mp = (ws + 8) % M_MORPH;
    int ms = ws % M_MORPH;
    int tk = ws / M_MORPH;
    const bool lo = (lane < 32);

    float hreg = 0.f, c = 0.f;

#pragma unroll 1
    for (int s = ws; s < ce; s += 8) {
#pragma unroll
        for (int u = 0; u < 8; ++u) {
            const int su = s + u;
            const float x1 = q[u][0], x2 = q[u][1];
            {
                const int sp = su + 8;
                int rp;
                if (dm == 1)      rp = sp + 11 - 2 * mp;
                else if (dm == 2) rp = N - 1 - sp;
                else              rp = sp;
                rp = (sp < ce) ? rp : 0;
                q[u] = *(const f32x2*)(Xc + (size_t)rp * 256);
                ++mp; if (mp == M_MORPH) mp = 0;
            }

            sh[lane] = hreg;
            f32x2 hp[16];
            {
                const f32x2* shv = (const f32x2*)sh;
#pragma unroll
                for (int i = 0; i < 16; ++i) hp[i] = shv[i];
            }

            f32x2 a01 = {x1, 0.f}, a23 = {0.f, 0.f};
            f32x2 b01 = {x2, 0.f}, b23 = {0.f, 0.f};
#pragma unroll
            for (int i = 0; i < 8; ++i) {
                PKFMA(a01, wa[2 * i],     hp[2 * i]);
                PKFMA(a23, wa[2 * i + 1], hp[2 * i + 1]);
                PKFMA(b01, wb[2 * i],     hp[2 * i]);
                PKFMA(b23, wb[2 * i + 1], hp[2 * i + 1]);
            }
            const float g1 = (a01[0] + a01[1]) + (a23[0] + a23[1]);
            const float g2 = (b01[0] + b01[1]) + (b23[0] + b23[1]);

            const float s1 = sigmoidf_(g1);
            const float uu = sigmoidf_(lo ? 2.f * g2 : g2);
            const float t2 = lo ? 2.f * uu - 1.f : uu;

            float si, sf, tg, so;
            half_swap(s1, si, sf);
            half_swap(t2, tg, so);

            c = sf * c + si * tg;
            const float th = 2.f * sigmoidf_(2.f * c) - 1.f;
            hreg = so * th;

            if (!store_last) {
                if (su >= cs) {
                    int r = su;
                    if (dm == 1)      r = su + 11 - 2 * ms;
                    else if (dm == 2) r = N - 1 - su;
                    if (lo) Hout[(size_t)r * 64 + dir * 32 + lane] = hreg;
                }
            } else {
                const bool last = (dm == 1) ? (ms == 0) : (ms == 11);
                if (su >= cs && last) {
                    if (lo) Hout[(size_t)tk * 64 + dir * 32 + lane] = hreg;
                }
            }
            ++ms; if (ms == M_MORPH) { ms = 0; ++tk; }
        }
    }
}

// ---------------------------------------------------------------------------
// DUAL-chunk LSTM recurrence — MORPH level. One wave processes two adjacent
// chunks (csA = bid*2*Lc, csB = csA+Lc) of the SAME direction: shared Whh
// registers, interleaved dependency chains (chunk B's FMAs/trans fill chunk
// A's LDS-turnaround/trans stalls). Bit-identical per-chunk numerics: same
// boundaries, same order; mismatched warm-up spans (block 0) handled by
// clamped loads + predicated stores; post-ce garbage touches only dead regs.
// Grid: NMORPH/(2*Lc) x 2  (1 wave/SIMD; waves_per_eu(1,1) = full VGPR).
// ---------------------------------------------------------------------------
__global__ __launch_bounds__(64)
__attribute__((amdgpu_waves_per_eu(1, 1)))
void lstm_chain2(const float* __restrict__ Xall,
                 const float* __restrict__ Whhall,
                 float* __restrict__ Hout,
                 int N, int Lc, int Wu,
                 int bwd_mode, int store_last) {
    __shared__ __align__(16) float sh[128];
    const int lane = threadIdx.x;
    const int dir = blockIdx.y;
    const int dm = dir ? bwd_mode : 0;
    const float* Whh = Whhall + dir * 128 * 32;

    const int csA = blockIdx.x * (2 * Lc);
    const int csB = csA + Lc;
    int ceA = csA + Lc, ceB = csB + Lc;
    int wsA = csA - Wu; if (wsA < 0) wsA = 0;
    int wsB = csB - Wu; if (wsB < 0) wsB = 0;
    const int stepsA = ceA - wsA, stepsB = ceB - wsB;
    const int nsteps = (stepsA > stepsB) ? stepsA : stepsB;  // mult of 8

    f32x2 wa[16], wb[16];
    {
        const f32x2* w1 = (const f32x2*)(Whh + lane * 32);
        const f32x2* w2 = (const f32x2*)(Whh + (lane + 64) * 32);
#pragma unroll
        for (int i = 0; i < 16; ++i) { wa[i] = w1[i]; wb[i] = w2[i]; }
    }
#pragma unroll
    for (int i = 0; i < 16; ++i) {
        asm volatile("" : "+v"(wa[i]));
        asm volatile("" : "+v"(wb[i]));
    }

    const float* Xc = Xall + dir * 128 + lane * 2;

    f32x2 qA[8], qB[8];
#pragma unroll
    for (int p = 0; p < 8; ++p) {
        int spA = wsA + p; if (spA > ceA - 1) spA = ceA - 1;
        int spB = wsB + p; if (spB > ceB - 1) spB = ceB - 1;
        qA[p] = *(const f32x2*)(Xc + (size_t)rowof(spA, dm, N) * 256);
        qB[p] = *(const f32x2*)(Xc + (size_t)rowof(spB, dm, N) * 256);
    }

    const bool lo = (lane < 32);
    float hA = 0.f, cA = 0.f, hB = 0.f, cB = 0.f;

#pragma unroll 1
    for (int s = 0; s < nsteps; s += 8) {
#pragma unroll
        for (int u = 0; u < 8; ++u) {
            const int suA = wsA + s + u;
            const int suB = wsB + s + u;
            const float xA1 = qA[u][0], xA2 = qA[u][1];
            const float xB1 = qB[u][0], xB2 = qB[u][1];

            // unconditional prefetch, clamped past chunk end (values unused)
            {
                const int spA = suA + 8;
                int rp;
                if (dm == 1)      rp = spA + 11 - 2 * (spA % M_MORPH);
                else if (dm == 2) rp = N - 1 - spA;
                else              rp = spA;
                rp = (spA < ceA) ? rp : 0;
                qA[u] = *(const f32x2*)(Xc + (size_t)rp * 256);
            }
            {
                const int spB = suB + 8;
                int rp;
                if (dm == 1)      rp = spB + 11 - 2 * (spB % M_MORPH);
                else if (dm == 2) rp = N - 1 - spB;
                else              rp = spB;
                rp = (spB < ceB) ? rp : 0;
                qB[u] = *(const f32x2*)(Xc + (size_t)rp * 256);
            }

            // h broadcast via LDS, both chunks (A half, B half)
            sh[lane] = hA;
            sh[64 + lane] = hB;
            f32x2 hpA[16], hpB[16];
            {
                const f32x2* shv = (const f32x2*)sh;
#pragma unroll
                for (int i = 0; i < 16; ++i) { hpA[i] = shv[i]; hpB[i] = shv[16 + i]; }
            }

            // gate pre-activations, interleaved A/B (shared weights)
            f32x2 aA01 = {xA1, 0.f}, aA23 = {0.f, 0.f};
            f32x2 bA01 = {xA2, 0.f}, bA23 = {0.f, 0.f};
            f32x2 aB01 = {xB1, 0.f}, aB23 = {0.f, 0.f};
            f32x2 bB01 = {xB2, 0.f}, bB23 = {0.f, 0.f};
#pragma unroll
            for (int i = 0; i < 8; ++i) {
                PKFMA(aA01, wa[2 * i],     hpA[2 * i]);
                PKFMA(aB01, wa[2 * i],     hpB[2 * i]);
                PKFMA(aA23, wa[2 * i + 1], hpA[2 * i + 1]);
                PKFMA(aB23, wa[2 * i + 1], hpB[2 * i + 1]);
                PKFMA(bA01, wb[2 * i],     hpA[2 * i]);
                PKFMA(bB01, wb[2 * i],     hpB[2 * i]);
                PKFMA(bA23, wb[2 * i + 1], hpA[2 * i + 1]);
                PKFMA(bB23, wb[2 * i + 1], hpB[2 * i + 1]);
            }
            const float gA1 = (aA01[0] + aA01[1]) + (aA23[0] + aA23[1]);
            const float gA2 = (bA01[0] + bA01[1]) + (bA23[0] + bA23[1]);
            const float gB1 = (aB01[0] + aB01[1]) + (aB23[0] + aB23[1]);
            const float gB2 = (bB01[0] + bB01[1]) + (bB23[0] + bB23[1]);

            // activations A
            const float sA1 = sigmoidf_(gA1);
            const float uA  = sigmoidf_(lo ? 2.f * gA2 : gA2);
            const float tA2 = lo ? 2.f * uA - 1.f : uA;
            // activations B (independent -> overlaps A's trans latency)
            const float sB1 = sigmoidf_(gB1);
            const float uB  = sigmoidf_(lo ? 2.f * gB2 : gB2);
            const float tB2 = lo ? 2.f * uB - 1.f : uB;

            float siA, sfA, tgA, soA, siB, sfB, tgB, soB;
            half_swap(sA1, siA, sfA);
            half_swap(tA2, tgA, soA);
            half_swap(sB1, siB, sfB);
            half_swap(tB2, tgB, soB);

            cA = sfA * cA + siA * tgA;
            cB = sfB * cB + siB * tgB;
            const float thA = 2.f * sigmoidf_(2.f * cA) - 1.f;
            const float thB = 2.f * sigmoidf_(2.f * cB) - 1.f;
            hA = soA * thA;
            hB = soB * thB;

            // conditional stores (wave-uniform predicates)
            if (!store_last) {
                if (suA >= csA && suA < ceA) {
                    int r = suA;
                    if (dm == 1)      r = suA + 11 - 2 * (suA % M_MORPH);
                    else if (dm == 2) r = N - 1 - suA;
                    if (lo) Hout[(size_t)r * 64 + dir * 32 + lane] = hA;
                }
                if (suB >= csB && suB < ceB) {
                    int r = suB;
                    if (dm == 1)      r = suB + 11 - 2 * (suB % M_MORPH);
                    else if (dm == 2) r = N - 1 - suB;
                    if (lo) Hout[(size_t)r * 64 + dir * 32 + lane] = hB;
                }
            } else {
                const int msA = suA % M_MORPH, msB = suB % M_MORPH;
                const bool lastA = (dm == 1) ? (msA == 0) : (msA == 11);
                const bool lastB = (dm == 1) ? (msB == 0) : (msB == 11);
                if (suA >= csA && suA < ceA && lastA) {
                    if (lo) Hout[(size_t)(suA / M_MORPH) * 64 + dir * 32 + lane] = hA;
                }
                if (suB >= csB && suB < ceB && lastB) {
                    if (lo) Hout[(size_t)(suB / M_MORPH) * 64 + dir * 32 + lane] = hB;
                }
            }
        }
    }
}

// ---------------------------------------------------------------------------
// input_embs[t] = [tok_vec(64) | dp_emb[dp_in[t]](4) | feat[t](1) | 0 pad],
// stride 96.
// ---------------------------------------------------------------------------
__global__ __launch_bounds__(256) void build_embs(const float* __restrict__ tokvec,
                                                  const float* __restrict__ dp_emb,
                                                  const int* __restrict__ dp_in,
                                                  const float* __restrict__ feat,
                                                  float* __restrict__ embs) {
    const int idx = blockIdx.x * 256 + threadIdx.x;
    if (idx >= T_TOK * 96) return;
    const int t = idx / 96, i = idx % 96;
    float v;
    if (i < 64)      v = tokvec[(size_t)t * 64 + i];
    else if (i < 68) v = dp_emb[dp_in[t] * 4 + (i - 64)];
    else if (i == 68) v = feat[t];
    else             v = 0.f;
    embs[idx] = v;
}

// ---------------------------------------------------------------------------
__global__ __launch_bounds__(64) void epilogue_k(const float* __restrict__ Ht1,
                                                 const float* __restrict__ Wout,
                                                 const float* __restrict__ bout,
                                                 const int* __restrict__ maskp,
                                                 float* __restrict__ out) {
    const int t = blockIdx.x;
    const int lane = threadIdx.x;
    float acc = -1e30f;
    if (lane < 44) {
        acc = bout[lane];
        const float* wr = Wout + lane * 64;
        const float* hr = Ht1 + (size_t)t * 64;
#pragma unroll
        for (int k = 0; k < 64; ++k) acc += hr[k] * wr[k];
        if (lane == 43 && maskp[t] <= 0) acc = 1.0f;
        acc = fmaxf(acc, 0.f);
    }
    float mx = acc;
#pragma unroll
    for (int off = 32; off >= 1; off >>= 1) mx = fmaxf(mx, __shfl_xor(mx, off));
    const float e = (lane < 44) ? __expf(acc - mx) : 0.f;
    float ssum = e;
#pragma unroll
    for (int off = 32; off >= 1; off >>= 1) ssum += __shfl_xor(ssum, off);
    if (lane < 44) out[(size_t)t * 44 + lane] = e / ssum;
}

// ---------------------------------------------------------------------------
extern "C" void kernel_launch(void* const* d_in, const int* in_sizes, int n_in,
                              void* d_out, int out_size, void* d_ws, size_t ws_size,
                              hipStream_t stream) {
    const float* morp  = (const float*)d_in[0];
    const float* feat  = (const float*)d_in[1];
    const float* dpemb = (const float*)d_in[2];
    const float* mWih0 = (const float*)d_in[3];
    const float* mWhh0 = (const float*)d_in[4];
    const float* mb0   = (const float*)d_in[5];
    const float* mWih1 = (const float*)d_in[6];
    const float* mWhh1 = (const float*)d_in[7];
    const float* mb1   = (const float*)d_in[8];
    const float* tWih0 = (const float*)d_in[9];
    const float* tWhh0 = (const float*)d_in[10];
    const float* tb0   = (const float*)d_in[11];
    const float* tWih1 = (const float*)d_in[12];
    const float* tWhh1 = (const float*)d_in[13];
    const float* tb1   = (const float*)d_in[14];
    const float* Wout  = (const float*)d_in[15];
    const float* bout  = (const float*)d_in[16];
    const int*   dpin  = (const int*)d_in[17];
    const int*   maskp = (const int*)d_in[18];
    float* out = (float*)d_out;

    float* w = (float*)d_ws;
    size_t off = 0;
    float* X0     = w + off; off += (size_t)NMORPH * 256;   // paired-layout X
    float* Hcat0  = w + off; off += (size_t)NMORPH * 64;
    float* tokvec = w + off; off += (size_t)T_TOK * 64;
    float* embs   = w + off; off += (size_t)T_TOK * 96;
    float* Ht0    = w + off; off += (size_t)T_TOK * 64;
    float* Ht1    = w + off; off += (size_t)T_TOK * 64;
    unsigned short* Bh = (unsigned short*)(w + off); off += 256 * 128 / 2;
    unsigned short* Bl = (unsigned short*)(w + off); off += 256 * 128 / 2;
    float* bcat   = w + off; off += 256;
    float* Xt = X0;
    (void)ws_size; (void)in_sizes; (void)n_in; (void)out_size;

    // ---- morpheme-level BiLSTM (chains of length 98304), dual-chunk ----
    prep_B<<<256, 128, 0, stream>>>(mWih0, mb0, Bh, Bl, bcat, 100, 128);
    gemm_mfma<100, 128, 100><<<NMORPH / 128, 256, 0, stream>>>(morp, Bh, Bl, bcat, X0);
    lstm_chain2<<<dim3(NMORPH / 192, 2), 64, 0, stream>>>(X0, mWhh0, Hcat0, NMORPH, 96, 64, 1, 0);
    prep_B<<<256, 64, 0, stream>>>(mWih1, mb1, Bh, Bl, bcat, 64, 64);
    gemm_mfma<64, 64, 64><<<NMORPH / 128, 256, 0, stream>>>(Hcat0, Bh, Bl, bcat, X0);
    lstm_chain2<<<dim3(NMORPH / 192, 2), 64, 0, stream>>>(X0, mWhh1, tokvec, NMORPH, 96, 64, 1, 1);

    // ---- token-level BiLSTM (chains of length 8192), single-chunk ----
    build_embs<<<(T_TOK * 96) / 256, 256, 0, stream>>>(tokvec, dpemb, dpin, feat, embs);
    prep_B<<<256, 96, 0, stream>>>(tWih0, tb0, Bh, Bl, bcat, 69, 96);
    gemm_mfma<96, 96, 96><<<T_TOK / 128, 256, 0, stream>>>(embs, Bh, Bl, bcat, Xt);
    lstm_chain<<<dim3(T_TOK / 32, 2), 64, 0, stream>>>(Xt, tWhh0, Ht0, T_TOK, 32, 64, 2, 0);
    prep_B<<<256, 64, 0, stream>>>(tWih1, tb1, Bh, Bl, bcat, 64, 64);
    gemm_mfma<64, 64, 64><<<T_TOK / 128, 256, 0, stream>>>(Ht0, Bh, Bl, bcat, Xt);
    lstm_chain<<<dim3(T_TOK / 32, 2), 64, 0, stream>>>(Xt, tWhh1, Ht1, T_TOK, 32, 64, 2, 0);

    // ---- output head ----
    epilogue_k<<<T_TOK, 64, 0, stream>>>(Ht1, Wout, bout, maskp, out);
}

// Round 8
// 400.739 us; speedup vs baseline: 1.1873x; 1.1873x over previous
//
#include <hip/hip_runtime.h>

#define T_TOK   8192
#define M_MORPH 12
#define NMORPH  (T_TOK * M_MORPH)   // 98304

typedef float f32x4 __attribute__((ext_vector_type(4)));
typedef float f32x2 __attribute__((ext_vector_type(2)));
typedef short s16x8 __attribute__((ext_vector_type(8)));

__device__ __forceinline__ float sigmoidf_(float x) {
    return __fdividef(1.f, 1.f + __expf(-x));
}

__device__ __forceinline__ int rowof(int s, int mode, int N) {
    if (mode == 0) return s;
    if (mode == 1) { int m = s % M_MORPH; return s + (M_MORPH - 1) - 2 * m; }
    return N - 1 - s;
}

// packed fp32 FMA: acc = w*h + acc (exact IEEE fma per lane-half, full rate)
#define PKFMA(acc, w, h) \
    asm("v_pk_fma_f32 %0, %1, %2, %0" : "+v"(acc) : "v"(w), "v"(h))

// lane-half swap broadcast (1 instr, no LDS): lo_b = lanes0..31 value in both
// halves; hi_b = lanes32..63 value in both halves.
__device__ __forceinline__ void half_swap(float v, float& lo_b, float& hi_b) {
#if __has_builtin(__builtin_amdgcn_permlane32_swap)
    auto r = __builtin_amdgcn_permlane32_swap(__float_as_uint(v), __float_as_uint(v),
                                              false, false);
    lo_b = __uint_as_float((unsigned)r[0]);
    hi_b = __uint_as_float((unsigned)r[1]);
#else
    const float e = __shfl_xor(v, 32);
    const bool lo = ((threadIdx.x & 63) < 32);
    lo_b = lo ? v : e;
    hi_b = lo ? e : v;
#endif
}

// ---------------------------------------------------------------------------
// Pre-split LSTM input weights into frag-ready bf16 hi/lo tables.
// ---------------------------------------------------------------------------
__global__ void prep_B(const float* __restrict__ W, const float* __restrict__ b,
                       unsigned short* __restrict__ Bh, unsigned short* __restrict__ Bl,
                       float* __restrict__ bcat, int WK, int KPAD) {
    const int n = blockIdx.x;        // 0..255
    const int k = threadIdx.x;       // 0..KPAD-1
    const int dir = n >> 7, r = n & 127;
    float v = (k < WK) ? W[(size_t)(dir * 128 + r) * WK + k] : 0.f;
    unsigned int u = __float_as_uint(v);
    unsigned short hb = (unsigned short)(u >> 16);
    float fh = __uint_as_float(u & 0xFFFF0000u);
    float lo = v - fh;
    unsigned short lb = (unsigned short)(__float_as_uint(lo) >> 16);
    Bh[(size_t)n * KPAD + k] = hb;
    Bl[(size_t)n * KPAD + k] = lb;
    if (k == 0) bcat[n] = b[dir * 128 + r];
}

// ---------------------------------------------------------------------------
// X[r][256] = A[r][AS](first KACT) @ Wcat[256][K]^T + bcat via split-bf16
// MFMA (hi*hi + hi*lo + lo*hi).
//
// PAIRED OUTPUT LAYOUT (round-5): column c is stored at
//   d*128 + (c%64)*2 + ((c%128)/64),  d = c/128
// so the chain's lane l reads its two gate pre-activations as ONE dwordx2.
// ---------------------------------------------------------------------------
template <int KACT, int KPAD, int AS>
__global__ __launch_bounds__(256, 2) void gemm_mfma(const float* __restrict__ A,
                                                    const unsigned short* __restrict__ Bh,
                                                    const unsigned short* __restrict__ Bl,
                                                    const float* __restrict__ bc,
                                                    float* __restrict__ X) {
    const int lane = threadIdx.x & 63;
    const int wave = threadIdx.x >> 6;
    const int col = lane & 15;
    const int kc  = (lane >> 4) * 8;
    const int row0 = blockIdx.x * 128 + wave * 32;

    f32x4 acc[2][16];
#pragma unroll
    for (int ct = 0; ct < 16; ++ct) {
        const float bv = bc[ct * 16 + col];
        f32x4 v; v[0] = bv; v[1] = bv; v[2] = bv; v[3] = bv;
        acc[0][ct] = v; acc[1][ct] = v;
    }

    const float* a0 = A + (size_t)(row0 + col) * AS;
    const float* a1 = A + (size_t)(row0 + 16 + col) * AS;

#pragma unroll
    for (int ks = 0; ks < KPAD / 32; ++ks) {
        const int kb = ks * 32 + kc;
        s16x8 ah[2], al[2];
#pragma unroll
        for (int rt = 0; rt < 2; ++rt) {
            const float* ap = (rt ? a1 : a0) + kb;
            float av[8];
#pragma unroll
            for (int h = 0; h < 2; ++h) {
                float4 t; t.x = t.y = t.z = t.w = 0.f;
                if ((ks + 1) * 32 <= KACT || kb + h * 4 < KACT)
                    t = *(const float4*)(ap + h * 4);
                av[h * 4 + 0] = t.x; av[h * 4 + 1] = t.y;
                av[h * 4 + 2] = t.z; av[h * 4 + 3] = t.w;
            }
#pragma unroll
            for (int j = 0; j < 8; ++j) {
                const unsigned int u = __float_as_uint(av[j]);
                const unsigned short hb = (unsigned short)(u >> 16);
                const float fh = __uint_as_float(u & 0xFFFF0000u);
                const float lov = av[j] - fh;
                const unsigned short lb = (unsigned short)(__float_as_uint(lov) >> 16);
                ah[rt][j] = (short)hb;
                al[rt][j] = (short)lb;
            }
        }

        const unsigned short* bhp = Bh + (size_t)col * KPAD + kb;
        const unsigned short* blp = Bl + (size_t)col * KPAD + kb;
#pragma unroll
        for (int ct = 0; ct < 16; ++ct) {
            const s16x8 bh8 = *(const s16x8*)(bhp + (size_t)ct * 16 * KPAD);
            const s16x8 bl8 = *(const s16x8*)(blp + (size_t)ct * 16 * KPAD);
#pragma unroll
            for (int rt = 0; rt < 2; ++rt) {
                acc[rt][ct] = __builtin_amdgcn_mfma_f32_16x16x32_bf16(ah[rt], bh8, acc[rt][ct], 0, 0, 0);
                acc[rt][ct] = __builtin_amdgcn_mfma_f32_16x16x32_bf16(ah[rt], bl8, acc[rt][ct], 0, 0, 0);
                acc[rt][ct] = __builtin_amdgcn_mfma_f32_16x16x32_bf16(al[rt], bh8, acc[rt][ct], 0, 0, 0);
            }
        }
    }

    const int r_in = (lane >> 4) * 4;
#pragma unroll
    for (int rt = 0; rt < 2; ++rt)
#pragma unroll
        for (int ct = 0; ct < 16; ++ct) {
            const int c = ct * 16 + col;           // original column
            const int d = c >> 7;
            const int cm = c & 127;
            const int nc = d * 128 + (cm & 63) * 2 + (cm >> 6);  // paired
#pragma unroll
            for (int i = 0; i < 4; ++i)
                X[(size_t)(row0 + rt * 16 + r_in + i) * 256 + nc] = acc[rt][ct][i];
        }
}

// ---------------------------------------------------------------------------
// LSTM chain step-body, fully specialized on DM (0=fwd, 1=morph-bwd,
// 2=plain-bwd) and SL (store-last-morpheme). r6 structure (proven best:
// 2 waves/SIMD, 1 chunk/wave, depth-8 unconditional prefetch, conditional
// wave-uniform stores) with the per-step index arithmetic reduced to
// incrementally-maintained pointers/rows (constant deltas; morph wrap
// = +23 rows) and 8x ds_read_b128 h-broadcast (zero-mov sub-pair feed).
// ---------------------------------------------------------------------------
template <int DM, int SL>
__device__ __forceinline__ void chain_body(
    const float* __restrict__ Xc, float* __restrict__ HoutLane,
    const bool lo, const int lane,
    f32x2 (&wa)[16], f32x2 (&wb)[16], float* sh,
    const int N, const int cs, const int ce, const int ws)
{
    // per-lane activation constants: lo: sig(2g)*2-1 ; hi: sig(g)
    const float cg = lo ? 2.f : 1.f;
    const float ca = lo ? -1.f : 0.f;

    f32x2 q[8];
#pragma unroll
    for (int p = 0; p < 8; ++p) {
        const int rp = rowof(ws + p, DM, N);
        q[p] = *(const f32x2*)(Xc + (size_t)rp * 256);
    }

    // prefetch state for sp = ws+8
    int mp = (ws + 8) % M_MORPH;             // used only when DM==1
    int pb;                                  // prefetch row byte offset
    {
        const int sp0 = ws + 8;
        int rp0;
        if (DM == 1)      rp0 = sp0 + 11 - 2 * mp;
        else if (DM == 2) rp0 = N - 1 - sp0;
        else              rp0 = sp0;
        pb = rp0 * 1024;
    }

    // store state
    int ms = ws % M_MORPH;                   // morph phase (DM==1 or SL)
    int rs;                                  // store row (non-SL)
    if (DM == 1)      rs = ws + 11 - 2 * ms;
    else if (DM == 2) rs = N - 1 - ws;
    else              rs = ws;
    int tk = ws / M_MORPH;                   // SL only

    float hreg = 0.f, c = 0.f;

#pragma unroll 1
    for (int s = ws; s < ce; s += 8) {
#pragma unroll
        for (int u = 0; u < 8; ++u) {
            const int su = s + u;
            const float x1 = q[u][0], x2 = q[u][1];

            // unconditional prefetch; offset clamped to row 0 past chunk end
            {
                const int sp = su + 8;
                const int ob = (sp < ce) ? pb : 0;
                q[u] = *(const f32x2*)((const char*)Xc + ob);
                if (DM == 1) {
                    if (mp == 11) { mp = 0; pb += 23 * 1024; }
                    else          { ++mp; pb -= 1024; }
                } else if (DM == 2) { pb -= 1024; }
                else                { pb += 1024; }
            }

            // h broadcast via LDS: 1 write + 8 b128 reads (sub-pairs feed
            // PKFMA directly via shufflevector = subregister, no movs)
            sh[lane] = hreg;
            f32x4 hq[8];
            {
                const f32x4* s4 = (const f32x4*)sh;
#pragma unroll
                for (int i = 0; i < 8; ++i) hq[i] = s4[i];
            }

            f32x2 a01 = {x1, 0.f}, a23 = {0.f, 0.f};
            f32x2 b01 = {x2, 0.f}, b23 = {0.f, 0.f};
#pragma unroll
            for (int i = 0; i < 8; ++i) {
                f32x2 hlo = __builtin_shufflevector(hq[i], hq[i], 0, 1);
                f32x2 hhi = __builtin_shufflevector(hq[i], hq[i], 2, 3);
                PKFMA(a01, wa[2 * i],     hlo);
                PKFMA(a23, wa[2 * i + 1], hhi);
                PKFMA(b01, wb[2 * i],     hlo);
                PKFMA(b23, wb[2 * i + 1], hhi);
            }
            const float g1 = (a01[0] + a01[1]) + (a23[0] + a23[1]);  // i|f
            const float g2 = (b01[0] + b01[1]) + (b23[0] + b23[1]);  // g|o

            const float s1 = sigmoidf_(g1);
            const float uu = sigmoidf_(cg * g2);
            const float t2 = fmaf(cg, uu, ca);        // tanh(g) | sig(o)

            float si, sf, tg, so;
            half_swap(s1, si, sf);
            half_swap(t2, tg, so);

            c = sf * c + si * tg;
            const float th = 2.f * sigmoidf_(2.f * c) - 1.f;
            hreg = so * th;

            // conditional store (wave-uniform predicates)
            if (!SL) {
                if (su >= cs) {
                    if (lo) HoutLane[(size_t)rs * 64] = hreg;
                }
            } else {
                const bool last = (DM == 1) ? (ms == 0) : (ms == 11);
                if (su >= cs && last) {
                    if (lo) HoutLane[(size_t)tk * 64] = hreg;
                }
            }

            // advance store state (constant deltas)
            if (DM == 1) {
                if (ms == 11) { ms = 0; ++tk; rs += 23; }
                else          { ++ms; --rs; }
            } else if (DM == 2) {
                --rs;
            } else {
                ++rs;
                if (SL) { if (ms == 11) { ms = 0; ++tk; } else ++ms; }
            }
        }
    }
}

// BDM: the dm used for dir==1 (dir==0 is always DM=0 forward).
template <int BDM, int SL>
__global__ __launch_bounds__(64)
__attribute__((amdgpu_waves_per_eu(2, 2)))
void lstm_chain_t(const float* __restrict__ Xall,
                  const float* __restrict__ Whhall,
                  float* __restrict__ Hout,
                  int N, int Lc, int Wu) {
    __shared__ __align__(16) float sh[64];
    const int lane = threadIdx.x;
    const int dir = blockIdx.y;
    const float* Whh = Whhall + dir * 128 * 32;

    const int cs = blockIdx.x * Lc;
    if (cs >= N) return;
    int ce = cs + Lc; if (ce > N) ce = N;
    int ws = cs - Wu; if (ws < 0) ws = 0;

    // weights as f32x2 pairs (rows lane / lane+64), pinned in registers
    f32x2 wa[16], wb[16];
    {
        const f32x2* w1 = (const f32x2*)(Whh + lane * 32);
        const f32x2* w2 = (const f32x2*)(Whh + (lane + 64) * 32);
#pragma unroll
        for (int i = 0; i < 16; ++i) { wa[i] = w1[i]; wb[i] = w2[i]; }
    }
#pragma unroll
    for (int i = 0; i < 16; ++i) {
        asm volatile("" : "+v"(wa[i]));
        asm volatile("" : "+v"(wb[i]));
    }

    const float* Xc = Xall + dir * 128 + lane * 2;  // paired layout
    float* HoutLane = Hout + dir * 32 + lane;
    const bool lo = (lane < 32);

    if (dir == 0)
        chain_body<0,   SL>(Xc, HoutLane, lo, lane, wa, wb, sh, N, cs, ce, ws);
    else
        chain_body<BDM, SL>(Xc, HoutLane, lo, lane, wa, wb, sh, N, cs, ce, ws);
}

// ---------------------------------------------------------------------------
// input_embs[t] = [tok_vec(64) | dp_emb[dp_in[t]](4) | feat[t](1) | 0 pad],
// stride 96.
// ---------------------------------------------------------------------------
__global__ __launch_bounds__(256) void build_embs(const float* __restrict__ tokvec,
                                                  const float* __restrict__ dp_emb,
                                                  const int* __restrict__ dp_in,
                                                  const float* __restrict__ feat,
                                                  float* __restrict__ embs) {
    const int idx = blockIdx.x * 256 + threadIdx.x;
    if (idx >= T_TOK * 96) return;
    const int t = idx / 96, i = idx % 96;
    float v;
    if (i < 64)      v = tokvec[(size_t)t * 64 + i];
    else if (i < 68) v = dp_emb[dp_in[t] * 4 + (i - 64)];
    else if (i == 68) v = feat[t];
    else             v = 0.f;
    embs[idx] = v;
}

// ---------------------------------------------------------------------------
__global__ __launch_bounds__(64) void epilogue_k(const float* __restrict__ Ht1,
                                                 const float* __restrict__ Wout,
                                                 const float* __restrict__ bout,
                                                 const int* __restrict__ maskp,
                                                 float* __restrict__ out) {
    const int t = blockIdx.x;
    const int lane = threadIdx.x;
    float acc = -1e30f;
    if (lane < 44) {
        acc = bout[lane];
        const float* wr = Wout + lane * 64;
        const float* hr = Ht1 + (size_t)t * 64;
#pragma unroll
        for (int k = 0; k < 64; ++k) acc += hr[k] * wr[k];
        if (lane == 43 && maskp[t] <= 0) acc = 1.0f;
        acc = fmaxf(acc, 0.f);
    }
    float mx = acc;
#pragma unroll
    for (int off = 32; off >= 1; off >>= 1) mx = fmaxf(mx, __shfl_xor(mx, off));
    const float e = (lane < 44) ? __expf(acc - mx) : 0.f;
    float ssum = e;
#pragma unroll
    for (int off = 32; off >= 1; off >>= 1) ssum += __shfl_xor(ssum, off);
    if (lane < 44) out[(size_t)t * 44 + lane] = e / ssum;
}

// ---------------------------------------------------------------------------
extern "C" void kernel_launch(void* const* d_in, const int* in_sizes, int n_in,
                              void* d_out, int out_size, void* d_ws, size_t ws_size,
                              hipStream_t stream) {
    const float* morp  = (const float*)d_in[0];
    const float* feat  = (const float*)d_in[1];
    const float* dpemb = (const float*)d_in[2];
    const float* mWih0 = (const float*)d_in[3];
    const float* mWhh0 = (const float*)d_in[4];
    const float* mb0   = (const float*)d_in[5];
    const float* mWih1 = (const float*)d_in[6];
    const float* mWhh1 = (const float*)d_in[7];
    const float* mb1   = (const float*)d_in[8];
    const float* tWih0 = (const float*)d_in[9];
    const float* tWhh0 = (const float*)d_in[10];
    const float* tb0   = (const float*)d_in[11];
    const float* tWih1 = (const float*)d_in[12];
    const float* tWhh1 = (const float*)d_in[13];
    const float* tb1   = (const float*)d_in[14];
    const float* Wout  = (const float*)d_in[15];
    const float* bout  = (const float*)d_in[16];
    const int*   dpin  = (const int*)d_in[17];
    const int*   maskp = (const int*)d_in[18];
    float* out = (float*)d_out;

    float* w = (float*)d_ws;
    size_t off = 0;
    float* X0     = w + off; off += (size_t)NMORPH * 256;   // paired-layout X
    float* Hcat0  = w + off; off += (size_t)NMORPH * 64;
    float* tokvec = w + off; off += (size_t)T_TOK * 64;
    float* embs   = w + off; off += (size_t)T_TOK * 96;
    float* Ht0    = w + off; off += (size_t)T_TOK * 64;
    float* Ht1    = w + off; off += (size_t)T_TOK * 64;
    unsigned short* Bh = (unsigned short*)(w + off); off += 256 * 128 / 2;
    unsigned short* Bl = (unsigned short*)(w + off); off += 256 * 128 / 2;
    float* bcat   = w + off; off += 256;
    float* Xt = X0;
    (void)ws_size; (void)in_sizes; (void)n_in; (void)out_size;

    // ---- morpheme-level BiLSTM (chains of length 98304) ----
    prep_B<<<256, 128, 0, stream>>>(mWih0, mb0, Bh, Bl, bcat, 100, 128);
    gemm_mfma<100, 128, 100><<<NMORPH / 128, 256, 0, stream>>>(morp, Bh, Bl, bcat, X0);
    lstm_chain_t<1, 0><<<dim3(NMORPH / 96, 2), 64, 0, stream>>>(X0, mWhh0, Hcat0, NMORPH, 96, 64);
    prep_B<<<256, 64, 0, stream>>>(mWih1, mb1, Bh, Bl, bcat, 64, 64);
    gemm_mfma<64, 64, 64><<<NMORPH / 128, 256, 0, stream>>>(Hcat0, Bh, Bl, bcat, X0);
    lstm_chain_t<1, 1><<<dim3(NMORPH / 96, 2), 64, 0, stream>>>(X0, mWhh1, tokvec, NMORPH, 96, 64);

    // ---- token-level BiLSTM (chains of length 8192) ----
    build_embs<<<(T_TOK * 96) / 256, 256, 0, stream>>>(tokvec, dpemb, dpin, feat, embs);
    prep_B<<<256, 96, 0, stream>>>(tWih0, tb0, Bh, Bl, bcat, 69, 96);
    gemm_mfma<96, 96, 96><<<T_TOK / 128, 256, 0, stream>>>(embs, Bh, Bl, bcat, Xt);
    lstm_chain_t<2, 0><<<dim3(T_TOK / 32, 2), 64, 0, stream>>>(Xt, tWhh0, Ht0, T_TOK, 32, 64);
    prep_B<<<256, 64, 0, stream>>>(tWih1, tb1, Bh, Bl, bcat, 64, 64);
    gemm_mfma<64, 64, 64><<<T_TOK / 128, 256, 0, stream>>>(Ht0, Bh, Bl, bcat, Xt);
    lstm_chain_t<2, 0><<<dim3(T_TOK / 32, 2), 64, 0, stream>>>(Xt, tWhh1, Ht1, T_TOK, 32, 64);

    // ---- output head ----
    epilogue_k<<<T_TOK, 64, 0, stream>>>(Ht1, Wout, bout, maskp, out);
}